// Round 10
// baseline (331.443 us; speedup 1.0000x reference)
//
#include <hip/hip_runtime.h>
#include <stdint.h>

typedef unsigned short u16;
typedef __bf16  bf16x8   __attribute__((ext_vector_type(8)));
typedef float   floatx4  __attribute__((ext_vector_type(4)));
typedef unsigned short ushortx4 __attribute__((ext_vector_type(4)));

__device__ __forceinline__ u16 f2bf(float f) {
  unsigned u = __builtin_bit_cast(unsigned, f);
  u += 0x7FFFu + ((u >> 16) & 1u);           // RNE; inputs are finite
  return (u16)(u >> 16);
}

#define GLD_LDS16(g, l)                                                        \
  __builtin_amdgcn_global_load_lds(                                            \
      (const __attribute__((address_space(1))) void*)(g),                      \
      (__attribute__((address_space(3))) void*)(l), 16, 0, 0)

// ---------------------------------------------------------------------------
// Kernel 0a: weights fp32 -> bf16 (verified).
// ---------------------------------------------------------------------------
__global__ __launch_bounds__(256) void cvt_w(
    const float* __restrict__ Wq, const float* __restrict__ Wk,
    const float* __restrict__ Wv, u16* __restrict__ dst)
{
  const int z = blockIdx.y;
  const float* src = (z == 0) ? Wq : (z == 1) ? Wk : Wv;
  u16* d = dst + (size_t)z * 262144;
  const int idx = (blockIdx.x * 256 + threadIdx.x) * 8;
  const float4 lo = *(const float4*)&src[idx];
  const float4 hi = *(const float4*)&src[idx + 4];
  union { u16 h[8]; uint4 v; } pk;
  pk.h[0] = f2bf(lo.x); pk.h[1] = f2bf(lo.y); pk.h[2] = f2bf(lo.z); pk.h[3] = f2bf(lo.w);
  pk.h[4] = f2bf(hi.x); pk.h[5] = f2bf(hi.y); pk.h[6] = f2bf(hi.z); pk.h[7] = f2bf(hi.w);
  *(uint4*)&d[idx] = pk.v;
}

// ---------------------------------------------------------------------------
// Kernel 0b: x fp32 -> bf16 (verified).
// ---------------------------------------------------------------------------
__global__ __launch_bounds__(256) void cvt_x(
    const float* __restrict__ X, u16* __restrict__ dst)
{
  const int idx = (blockIdx.x * 256 + threadIdx.x) * 8;
  const float4 lo = *(const float4*)&X[idx];
  const float4 hi = *(const float4*)&X[idx + 4];
  union { u16 h[8]; uint4 v; } pk;
  pk.h[0] = f2bf(lo.x); pk.h[1] = f2bf(lo.y); pk.h[2] = f2bf(lo.z); pk.h[3] = f2bf(lo.w);
  pk.h[4] = f2bf(hi.x); pk.h[5] = f2bf(hi.y); pk.h[6] = f2bf(hi.z); pk.h[7] = f2bf(hi.w);
  *(uint4*)&dst[idx] = pk.v;
}

// ---------------------------------------------------------------------------
// Kernel 1: fused QKV projection (verified r9).  z=0 -> q (pre-scaled by
// log2e/sqrt(512)), z=1 -> k, z=2 -> v^T (vt[d][b*S+s]).
// ---------------------------------------------------------------------------
__global__ __launch_bounds__(256, 2) void qkv_gemm(
    const u16* __restrict__ X16, const u16* __restrict__ Wb,
    u16* __restrict__ qo, u16* __restrict__ ko, u16* __restrict__ vto)
{
  __shared__ u16 As[128 * 32];
  __shared__ u16 Bs[128 * 32];

  const int tid = threadIdx.x;
  const int w  = tid >> 6, l = tid & 63;
  const int lr = l & 15, lq = l >> 4;
  const int lk = lq * 8;
  const int m0 = blockIdx.x * 128;
  const int n0 = blockIdx.y * 128;
  const int z  = blockIdx.z;
  const u16* W = Wb + (size_t)z * 262144;
  const int wm = (w & 1) * 64, wn = (w >> 1) * 64;

  floatx4 acc[4][4];
  const floatx4 fz = {0.f, 0.f, 0.f, 0.f};
#pragma unroll
  for (int i = 0; i < 4; ++i)
#pragma unroll
    for (int j = 0; j < 4; ++j) acc[i][j] = fz;

  for (int kk = 0; kk < 512; kk += 32) {
    __syncthreads();
#pragma unroll
    for (int i = 0; i < 2; ++i) {
      const int c = i * 256 + tid;
      const int row = c >> 2, c8 = (c & 3) * 8;
      GLD_LDS16(X16 + (size_t)(m0 + row) * 512 + kk + c8, &As[c * 8]);
      GLD_LDS16(W   + (size_t)(n0 + row) * 512 + kk + c8, &Bs[c * 8]);
    }
    __syncthreads();

    bf16x8 af[4], bfr[4];
#pragma unroll
    for (int t = 0; t < 4; ++t) {
      af[t]  = *(const bf16x8*)&As[(wm + t * 16 + lr) * 32 + lk];
      bfr[t] = *(const bf16x8*)&Bs[(wn + t * 16 + lr) * 32 + lk];
    }
#pragma unroll
    for (int i = 0; i < 4; ++i)
#pragma unroll
      for (int j = 0; j < 4; ++j)
        acc[i][j] = __builtin_amdgcn_mfma_f32_16x16x32_bf16(af[i], bfr[j],
                                                            acc[i][j], 0, 0, 0);
  }

  const int cr = lq * 4;   // C layout: col=lane&15, row=quad*4+reg
  if (z == 2) {
#pragma unroll
    for (int i = 0; i < 4; ++i)
#pragma unroll
      for (int j = 0; j < 4; ++j) {
        const int n = n0 + wn + j * 16 + lr;           // d
        const int m = m0 + wm + i * 16 + cr;           // key (b*4096+s)
        ushortx4 pk;
#pragma unroll
        for (int r = 0; r < 4; ++r) pk[r] = f2bf(acc[i][j][r]);
        *(ushortx4*)&vto[(size_t)n * 16384 + m] = pk;  // vt[d][b*S+s]
      }
  } else {
    u16* dst = (z == 0) ? qo : ko;
    const float sc = (z == 0) ? 0.06375871732f : 1.0f; // log2(e)/sqrt(512)
#pragma unroll
    for (int i = 0; i < 4; ++i)
#pragma unroll
      for (int j = 0; j < 4; ++j) {
        const int m = m0 + wm + i * 16 + cr;
        const int n = n0 + wn + j * 16 + lr;
#pragma unroll
        for (int r = 0; r < 4; ++r)
          dst[(size_t)(m + r) * 512 + n] = f2bf(acc[i][j][r] * sc);
      }
  }
}

// ---------------------------------------------------------------------------
// Kernel 2: P = exp2(q k^T - c), ORIENTATION SWAPPED: A = k (keys = m'),
// B = q (qrows = n'), C[key][qrow].  The C r-index then runs along keys ->
// P[qrow][key] stores become ushortx4 (16 instead of 64 scalar).  Static-max
// softmax (c = 12*log2e, verified r3-r9).  lsum accumulates the TRUNCATED
// bf16 values actually stored in P, so PV's normalization is self-consistent
// (quantization bias cancels row-wise).
// ---------------------------------------------------------------------------
__global__ __launch_bounds__(256, 2) void qk_exp(
    const u16* __restrict__ q, const u16* __restrict__ k,
    u16* __restrict__ S, float* __restrict__ lsum)
{
  __shared__ u16 As[128 * 32];   // keys
  __shared__ u16 Bs[128 * 32];   // qrows

  const int tid = threadIdx.x;
  const int w  = tid >> 6, l = tid & 63;
  const int lr = l & 15, lq = l >> 4;
  const int lk = lq * 8;
  const int m0 = blockIdx.x * 128;               // key within batch
  const int n0 = blockIdx.y * 128;               // q row within batch
  const int b  = blockIdx.z;
  const int wm = (w & 1) * 64, wn = (w >> 1) * 64;
  const size_t rb = (size_t)b * 4096;

  floatx4 acc[4][4];
  const floatx4 fz = {0.f, 0.f, 0.f, 0.f};
#pragma unroll
  for (int i = 0; i < 4; ++i)
#pragma unroll
    for (int j = 0; j < 4; ++j) acc[i][j] = fz;

  for (int kk = 0; kk < 512; kk += 32) {
    __syncthreads();
#pragma unroll
    for (int i = 0; i < 2; ++i) {
      const int c = i * 256 + tid;
      const int row = c >> 2, c8 = (c & 3) * 8;
      GLD_LDS16(k + (rb + m0 + row) * 512 + kk + c8, &As[c * 8]);
      GLD_LDS16(q + (rb + n0 + row) * 512 + kk + c8, &Bs[c * 8]);
    }
    __syncthreads();

    bf16x8 af[4], bfr[4];
#pragma unroll
    for (int t = 0; t < 4; ++t) {
      af[t]  = *(const bf16x8*)&As[(wm + t * 16 + lr) * 32 + lk];
      bfr[t] = *(const bf16x8*)&Bs[(wn + t * 16 + lr) * 32 + lk];
    }
#pragma unroll
    for (int i = 0; i < 4; ++i)
#pragma unroll
      for (int j = 0; j < 4; ++j)
        acc[i][j] = __builtin_amdgcn_mfma_f32_16x16x32_bf16(af[i], bfr[j],
                                                            acc[i][j], 0, 0, 0);
  }

  // ---- epilogue: exp2 -> truncate to bf16 -> ushortx4 stores + row sums ----
  const int cr = lq * 4;
  u16* Sb = S + ((size_t)b << 24);               // b * 4096 * 4096
  float rs[4] = {0.f, 0.f, 0.f, 0.f};            // per j (qrow fixed per lane)
#pragma unroll
  for (int i = 0; i < 4; ++i)
#pragma unroll
    for (int j = 0; j < 4; ++j) {
      const int qrow = n0 + wn + j * 16 + lr;
      const int key  = m0 + wm + i * 16 + cr;
      ushortx4 pk;
#pragma unroll
      for (int r = 0; r < 4; ++r) {
        const float p = __builtin_amdgcn_exp2f(acc[i][j][r] - 17.31234049f);
        const unsigned u = __builtin_bit_cast(unsigned, p);
        pk[r] = (u16)(u >> 16);                  // truncation (p in [0,1])
        rs[j] += __builtin_bit_cast(float, u & 0xffff0000u);  // matches stored
      }
      *(ushortx4*)&Sb[(size_t)qrow * 4096 + key] = pk;
    }
#pragma unroll
  for (int j = 0; j < 4; ++j) {
    float s = rs[j];                             // sum over this wave's 64 keys
    s += __shfl_xor(s, 16);
    s += __shfl_xor(s, 32);
    if (lq == 0)
      atomicAdd(&lsum[rb + n0 + wn + j * 16 + lr], s);
  }
}

// ---------------------------------------------------------------------------
// Kernel 3: O = (P V) / lsum, ORIENTATION SWAPPED: A = vt (d = m', 128-tile),
// B = P (qrows = n', 64-tile), C[d][qrow].  Grid (4,64,4) = 1024 blocks =
// 4/CU (m102 block-supply lever).  BK=64 (halves barrier rounds; LDS 24KB).
// Epilogue: 8 float4 stores with 1/lsum folded.
// ---------------------------------------------------------------------------
__global__ __launch_bounds__(256, 2) void pv(
    const u16* __restrict__ S, const u16* __restrict__ vt,
    const float* __restrict__ lsum, float* __restrict__ out)
{
  __shared__ u16 As[128 * 64];   // vt d-rows, 16KB
  __shared__ u16 Bs[64 * 64];    // P qrows, 8KB

  const int tid = threadIdx.x;
  const int w  = tid >> 6, l = tid & 63;
  const int lr = l & 15, lq = l >> 4;
  const int lk = lq * 8;
  const int m0 = blockIdx.x * 128;               // d
  const int n0 = blockIdx.y * 64;                // q row within batch
  const int b  = blockIdx.z;
  const int wm = (w & 1) * 64, wn = (w >> 1) * 32;
  const u16* Sb = S + ((size_t)b << 24);

  floatx4 acc[4][2];
  const floatx4 fz = {0.f, 0.f, 0.f, 0.f};
#pragma unroll
  for (int i = 0; i < 4; ++i)
#pragma unroll
    for (int j = 0; j < 2; ++j) acc[i][j] = fz;

  for (int kk = 0; kk < 4096; kk += 64) {
    __syncthreads();
#pragma unroll
    for (int i = 0; i < 4; ++i) {                // A: 1024 chunks
      const int c = i * 256 + tid;
      const int row = c >> 3, c8 = (c & 7) * 8;
      GLD_LDS16(vt + (size_t)(m0 + row) * 16384 + b * 4096 + kk + c8, &As[c * 8]);
    }
#pragma unroll
    for (int i = 0; i < 2; ++i) {                // B: 512 chunks
      const int c = i * 256 + tid;
      const int row = c >> 3, c8 = (c & 7) * 8;
      GLD_LDS16(Sb + (size_t)(n0 + row) * 4096 + kk + c8, &Bs[c * 8]);
    }
    __syncthreads();

#pragma unroll
    for (int ks = 0; ks < 2; ++ks) {             // 2 k-steps of 32
      bf16x8 af[4], bfr[2];
#pragma unroll
      for (int i = 0; i < 4; ++i)
        af[i] = *(const bf16x8*)&As[(wm + i * 16 + lr) * 64 + ks * 32 + lk];
#pragma unroll
      for (int j = 0; j < 2; ++j)
        bfr[j] = *(const bf16x8*)&Bs[(wn + j * 16 + lr) * 64 + ks * 32 + lk];
#pragma unroll
      for (int i = 0; i < 4; ++i)
#pragma unroll
        for (int j = 0; j < 2; ++j)
          acc[i][j] = __builtin_amdgcn_mfma_f32_16x16x32_bf16(af[i], bfr[j],
                                                              acc[i][j], 0, 0, 0);
    }
  }

  // ---- epilogue: fold 1/lsum, float4 stores into out[qrow][d] ----
  const int cr = lq * 4;
  float inv[2];
#pragma unroll
  for (int j = 0; j < 2; ++j)
    inv[j] = 1.0f / lsum[(size_t)b * 4096 + n0 + wn + j * 16 + lr];
#pragma unroll
  for (int i = 0; i < 4; ++i)
#pragma unroll
    for (int j = 0; j < 2; ++j) {
      const int qrow = n0 + wn + j * 16 + lr;
      const int d    = m0 + wm + i * 16 + cr;
      float4 o;
      o.x = acc[i][j][0] * inv[j];
      o.y = acc[i][j][1] * inv[j];
      o.z = acc[i][j][2] * inv[j];
      o.w = acc[i][j][3] * inv[j];
      *(float4*)&out[((size_t)b * 4096 + qrow) * 512 + d] = o;
    }
}

// ---------------------------------------------------------------------------
extern "C" void kernel_launch(void* const* d_in, const int* in_sizes, int n_in,
                              void* d_out, int out_size, void* d_ws, size_t ws_size,
                              hipStream_t stream) {
  (void)in_sizes; (void)n_in; (void)out_size; (void)ws_size;
  const float* x  = (const float*)d_in[0];
  const float* Wq = (const float*)d_in[1];
  const float* Wk = (const float*)d_in[2];
  const float* Wv = (const float*)d_in[3];
  float* out = (float*)d_out;
  u16* ws  = (u16*)d_ws;
  u16* qw  = ws;                                  // q row-major, 16 MB
  u16* kw  = qw + (size_t)16384 * 512;            // k row-major, 16 MB
  u16* vw  = kw + (size_t)16384 * 512;            // v^T [512][16384], 16 MB
  u16* x16 = vw + (size_t)16384 * 512;            // x bf16, 16 MB
  u16* wb  = x16 + (size_t)16384 * 512;           // weights bf16, 1.5 MB
  u16* Sp  = wb + (size_t)3 * 262144;             // P bf16 [4][4096][4096], 128 MB
  float* lsum = (float*)(Sp + ((size_t)4 << 24)); // [16384] fp32, 64 KB

  hipMemsetAsync(lsum, 0, 16384 * sizeof(float), stream);
  cvt_w<<<dim3(128, 3), dim3(256), 0, stream>>>(Wq, Wk, Wv, wb);
  cvt_x<<<dim3(4096), dim3(256), 0, stream>>>(x, x16);
  qkv_gemm<<<dim3(128, 4, 3), dim3(256), 0, stream>>>(x16, wb, qw, kw, vw);
  qk_exp<<<dim3(32, 32, 4), dim3(256), 0, stream>>>(qw, kw, Sp, lsum);
  pv<<<dim3(4, 64, 4), dim3(256), 0, stream>>>(Sp, vw, lsum, out);
}